// Round 1
// baseline (184.547 us; speedup 1.0000x reference)
//
#include <hip/hip_runtime.h>

#define BATCH 32
#define H 512
#define W 512
#define PAD 4
#define WIN 9
#define SEG 64
// final scalar = sum over pixels of ((1-cc1)+(1-cc2)) * 0.5 / (B*H*W)
#define SCALE (0.5f / 8388608.0f)

__global__ __launch_bounds__(256) void ncc_loss_kernel(
    const float* __restrict__ g1, const float* __restrict__ g2,
    const float* __restrict__ gf, float* __restrict__ out)
{
    const int x  = blockIdx.x * 256 + threadIdx.x;   // column, always < W
    const int y0 = blockIdx.y * SEG;                 // output row band start
    const int b  = blockIdx.z;
    const size_t base = (size_t)b * (H * W);
    const float* I1 = g1 + base;
    const float* I2 = g2 + base;
    const float* F  = gf + base;

    // 9-deep register ring of horizontal 9-sums for 8 quantities.
    // Indexed ONLY by compile-time-constant phase -> stays in VGPRs.
    float r1[WIN], r2[WIN], rf[WIN], r11[WIN], r22[WIN], rff[WIN], r1f[WIN], r2f[WIN];
#pragma unroll
    for (int i = 0; i < WIN; ++i) {
        r1[i]=0.f; r2[i]=0.f; rf[i]=0.f; r11[i]=0.f;
        r22[i]=0.f; rff[i]=0.f; r1f[i]=0.f; r2f[i]=0.f;
    }
    // running vertical sums (over the last 9 rows of horizontal sums)
    float v1=0.f,v2=0.f,vf=0.f,v11=0.f,v22=0.f,vff=0.f,v1f=0.f,v2f=0.f;
    float lsum = 0.f;
    const float inv_n = 1.0f / 81.0f;

    // 72 row-steps = 8 outer iters x 9 phases (ring index == phase)
    for (int os = 0; os < (SEG + WIN - 1) / WIN; ++os) {
#pragma unroll
        for (int ph = 0; ph < WIN; ++ph) {
            const int step = os * WIN + ph;
            const int yr = y0 - PAD + step;   // incoming raw row
            float s1=0.f,s2=0.f,sf=0.f,s11=0.f,s22=0.f,sff=0.f,s1f=0.f,s2f=0.f;
            if (yr >= 0 && yr < H) {          // uniform branch (zero vertical pad)
                const float* p1 = I1 + (size_t)yr * W;
                const float* p2 = I2 + (size_t)yr * W;
                const float* pf = F  + (size_t)yr * W;
#pragma unroll
                for (int dx = -PAD; dx <= PAD; ++dx) {
                    const int xx = x + dx;
                    const bool ok = ((unsigned)xx < (unsigned)W);  // zero horizontal pad
                    const float a = ok ? p1[xx] : 0.f;
                    const float c = ok ? p2[xx] : 0.f;
                    const float f = ok ? pf[xx] : 0.f;
                    s1 += a; s2 += c; sf += f;
                    s11 = fmaf(a, a, s11);
                    s22 = fmaf(c, c, s22);
                    sff = fmaf(f, f, sff);
                    s1f = fmaf(a, f, s1f);
                    s2f = fmaf(c, f, s2f);
                }
            }
            // slide vertical window: add incoming row, drop row from 9 steps ago
            v1  += s1  - r1[ph];  r1[ph]  = s1;
            v2  += s2  - r2[ph];  r2[ph]  = s2;
            vf  += sf  - rf[ph];  rf[ph]  = sf;
            v11 += s11 - r11[ph]; r11[ph] = s11;
            v22 += s22 - r22[ph]; r22[ph] = s22;
            vff += sff - rff[ph]; rff[ph] = sff;
            v1f += s1f - r1f[ph]; r1f[ph] = s1f;
            v2f += s2f - r2f[ph]; r2f[ph] = s2f;

            if (step >= WIN - 1) {            // window full: output row y = yr - PAD
                // cross = S_IJ - S_I*S_J/n ; var = S_II - S_I^2/n  (same algebra as ref)
                const float cross1 = v1f - v1 * vf * inv_n;
                const float var1   = v11 - v1 * v1 * inv_n;
                const float varf   = vff - vf * vf * inv_n;
                const float cross2 = v2f - v2 * vf * inv_n;
                const float var2   = v22 - v2 * v2 * inv_n;
                const float cc1 = cross1 * cross1 / (var1 * varf + 1e-5f);
                const float cc2 = cross2 * cross2 / (var2 * varf + 1e-5f);
                lsum += (2.0f - cc1 - cc2);   // (1-cc1)+(1-cc2)
            }
        }
    }

    // block reduction: wave shuffle -> LDS -> one atomic per block
#pragma unroll
    for (int off = 32; off > 0; off >>= 1)
        lsum += __shfl_down(lsum, off);
    __shared__ float wsum[4];
    const int lane = threadIdx.x & 63;
    const int wid  = threadIdx.x >> 6;
    if (lane == 0) wsum[wid] = lsum;
    __syncthreads();
    if (threadIdx.x == 0) {
        atomicAdd(out, (wsum[0] + wsum[1] + wsum[2] + wsum[3]) * SCALE);
    }
}

extern "C" void kernel_launch(void* const* d_in, const int* in_sizes, int n_in,
                              void* d_out, int out_size, void* d_ws, size_t ws_size,
                              hipStream_t stream) {
    const float* img1 = (const float*)d_in[0];
    const float* img2 = (const float*)d_in[1];
    const float* fimg = (const float*)d_in[2];
    float* out = (float*)d_out;

    // d_out is poisoned 0xAA before every timed launch -> zero it (capture-safe)
    hipMemsetAsync(out, 0, sizeof(float), stream);

    dim3 grid(W / 256, H / SEG, BATCH);   // (2, 8, 32) = 512 blocks
    ncc_loss_kernel<<<grid, dim3(256), 0, stream>>>(img1, img2, fimg, out);
}